// Round 8
// baseline (201.715 us; speedup 1.0000x reference)
//
#include <hip/hip_runtime.h>

typedef unsigned short u16;
typedef __bf16 bf16x8 __attribute__((ext_vector_type(8)));
typedef float f32x4 __attribute__((ext_vector_type(4)));

__device__ __forceinline__ float b2f(u16 v) {
    return __uint_as_float(((unsigned int)v) << 16);
}
__device__ __forceinline__ u16 f2b(float f) {
    unsigned int u = __float_as_uint(f);
    u += 0x7fffu + ((u >> 16) & 1u);   // RNE
    return (u16)(u >> 16);
}

// async global->LDS, 16B/lane. Global side may be per-lane addresses;
// LDS side is wave-uniform base + lane*16B.
__device__ __forceinline__ void ld_lds16(const u16* g, u16* l) {
    __builtin_amdgcn_global_load_lds(
        (__attribute__((address_space(1))) void*)(uintptr_t)(const void*)g,
        (__attribute__((address_space(3))) void*)l, 16, 0, 0);
}

// ---------------------------------------------------------------------------
// Weight pre-pack: f32 -> bf16, segments laid out contiguously in ws.
// [w1r 655360 | w1t 655360 | w2r 163840 | w2t 163840 | w3r 32768 | w3t 32768]
// ---------------------------------------------------------------------------
__global__ void pack_w_k(const float* __restrict__ w1r, const float* __restrict__ w1t,
                         const float* __restrict__ w2r, const float* __restrict__ w2t,
                         const float* __restrict__ w3r, const float* __restrict__ w3t,
                         u16* __restrict__ dst)
{
    size_t i = (size_t)blockIdx.x * 2048 + (size_t)threadIdx.x * 8;
    const float* src; size_t off;
    if (i < 655360)       { src = w1r; off = 0; }
    else if (i < 1310720) { src = w1t; off = 655360; }
    else if (i < 1474560) { src = w2r; off = 1310720; }
    else if (i < 1638400) { src = w2t; off = 1474560; }
    else if (i < 1671168) { src = w3r; off = 1638400; }
    else                  { src = w3t; off = 1671168; }
    const float4 lo = *(const float4*)(src + (i - off));
    const float4 hi = *(const float4*)(src + (i - off) + 4);
    ushort4 o0, o1;
    o0.x = f2b(lo.x); o0.y = f2b(lo.y); o0.z = f2b(lo.z); o0.w = f2b(lo.w);
    o1.x = f2b(hi.x); o1.y = f2b(hi.y); o1.z = f2b(hi.z); o1.w = f2b(hi.w);
    *(ushort4*)(dst + i) = o0;
    *(ushort4*)(dst + i + 4) = o1;
}

// ---------------------------------------------------------------------------
// 1-NN (f32, mimics np: d2 = rr[i] + qq[j] - 2*g), atomicMin on (d2||idx) key.
// ---------------------------------------------------------------------------
__global__ void knn_k(const float* __restrict__ t1, const float* __restrict__ t2,
                      unsigned long long* __restrict__ keys)
{
    __shared__ float4 ref[128];   // x,y,z,rr
    const int t = threadIdx.x;
    const int rs = blockIdx.x;
    const int qb = blockIdx.y;
    if (t < 128) {
        int i = rs * 128 + t;
        float x = t1[i], y = t1[8192 + i], z = t1[16384 + i];
        float rr = __fadd_rn(__fadd_rn(__fmul_rn(x, x), __fmul_rn(y, y)), __fmul_rn(z, z));
        ref[t] = make_float4(x, y, z, rr);
    }
    __syncthreads();

    float qx[8], qy[8], qz[8], qq[8], bestd[8];
    int besti[8];
    const int q0 = qb * 2048 + t;
#pragma unroll
    for (int j = 0; j < 8; ++j) {
        int q = q0 + j * 256;
        qx[j] = t2[q]; qy[j] = t2[8192 + q]; qz[j] = t2[16384 + q];
        qq[j] = __fadd_rn(__fadd_rn(__fmul_rn(qx[j], qx[j]), __fmul_rn(qy[j], qy[j])),
                          __fmul_rn(qz[j], qz[j]));
        bestd[j] = __uint_as_float(0x7f800000u);
        besti[j] = 0;
    }
    for (int i = 0; i < 128; ++i) {
        float4 r = ref[i];
        int ridx = rs * 128 + i;
#pragma unroll
        for (int j = 0; j < 8; ++j) {
            float g = __fmaf_rn(qz[j], r.z, __fmaf_rn(qy[j], r.y, __fmul_rn(qx[j], r.x)));
            float d2 = __fsub_rn(__fadd_rn(r.w, qq[j]), __fmul_rn(2.0f, g));
            if (d2 < bestd[j]) { bestd[j] = d2; besti[j] = ridx; }
        }
    }
#pragma unroll
    for (int j = 0; j < 8; ++j) {
        unsigned long long key =
            ((unsigned long long)__float_as_uint(bestd[j]) << 32) | (unsigned int)besti[j];
        atomicMin(&keys[q0 + j * 256], key);
    }
}

// ---------------------------------------------------------------------------
// Both transposes in one dispatch: z=0 emb1->e1t, z=1 emb2->e2t (stride 512).
// ---------------------------------------------------------------------------
__global__ void transpose_k(const float* __restrict__ e1, const float* __restrict__ e2,
                            u16* __restrict__ o1, u16* __restrict__ o2)
{
    __shared__ float tile[64][65];
    const float* in = blockIdx.z ? e2 : e1;
    u16* out = blockIdx.z ? o2 : o1;
    const int t = threadIdx.x;
    const int n0 = blockIdx.x * 64, f0 = blockIdx.y * 64;
    const int c = t & 63, r4 = t >> 6;
#pragma unroll
    for (int p = 0; p < 16; ++p) {
        int fr = p * 4 + r4;
        tile[fr][c] = in[(size_t)(f0 + fr) * 8192 + n0 + c];
    }
    __syncthreads();
    const int fc = (t & 15) * 4;    // f-chunk of 4
    const int nr4 = t >> 4;         // 16 n-rows covered per pass
#pragma unroll
    for (int p = 0; p < 4; ++p) {
        int nr = p * 16 + nr4;
        ushort4 o;
        o.x = f2b(tile[fc + 0][nr]); o.y = f2b(tile[fc + 1][nr]);
        o.z = f2b(tile[fc + 2][nr]); o.w = f2b(tile[fc + 3][nr]);
        *(ushort4*)&out[(size_t)(n0 + nr) * 512 + f0 + fc] = o;
    }
}

// ---------------------------------------------------------------------------
// gemm1: h1t[n][m] = relu( sum_k A[m][k]*B[n][k] + bias[m] ), A = [w1r|w1t]
// (1280x1024). B row n: k<512 = e1t[idx[n]][k] (gather folded into staging
// via per-lane global_load_lds addresses), k>=512 = e2t[n][k-512].
// 128x128 tile, BK=32, m97 structure.
// ---------------------------------------------------------------------------
__global__ __launch_bounds__(256) void gemm1_k(
    const u16* __restrict__ A,
    const float* __restrict__ b1r, const float* __restrict__ b1t,
    const unsigned long long* __restrict__ keys,
    const u16* __restrict__ e1t, const u16* __restrict__ e2t,
    u16* __restrict__ Ct)
{
    __shared__ __align__(16) u16 lds_a[128 * 32];
    __shared__ __align__(16) u16 lds_b[128 * 32];

    const int t = threadIdx.x;
    const int n0 = blockIdx.x * 128;
    const int m0 = blockIdx.y * 128;
    const int w = t >> 6, l = t & 63;
    const int sr = l >> 2, sc = (l & 3) * 8;

    const u16* gA0 = A + (size_t)(m0 + w * 32 + sr) * 1024 + sc;
    const u16* gA1 = gA0 + (size_t)16 * 1024;
    u16* lA0 = &lds_a[w * 1024];
    u16* lA1 = lA0 + 512;

    const int r0 = n0 + w * 32 + sr, r1 = r0 + 16;
    const int i0 = (int)(keys[r0] & 0xffffffffu);
    const int i1 = (int)(keys[r1] & 0xffffffffu);
    const u16* pI0 = e1t + (size_t)i0 * 512 + sc;   // indirect half (k<512)
    const u16* pI1 = e1t + (size_t)i1 * 512 + sc;
    const u16* pD0 = e2t + (size_t)r0 * 512 + sc;   // direct half (k>=512)
    const u16* pD1 = e2t + (size_t)r1 * 512 + sc;
    u16* lB0 = &lds_b[w * 1024];
    u16* lB1 = lB0 + 512;

    const int wm = (w & 1) * 64;
    const int wn = (w >> 1) * 64;
    const int lrow = l & 15, quad = l >> 4;
    const u16* fa = &lds_a[(wm + lrow) * 32 + quad * 8];
    const u16* fb = &lds_b[(wn + lrow) * 32 + quad * 8];

    f32x4 acc[4][4];
#pragma unroll
    for (int i = 0; i < 4; ++i)
#pragma unroll
        for (int j = 0; j < 4; ++j)
            acc[i][j] = (f32x4){0.f, 0.f, 0.f, 0.f};

    ld_lds16(gA0, lA0); ld_lds16(gA1, lA1);
    ld_lds16(pI0, lB0); ld_lds16(pI1, lB1);

    for (int kt = 0; kt < 1024; kt += 32) {
        __syncthreads();
        bf16x8 af[4], bfr[4];
#pragma unroll
        for (int i = 0; i < 4; ++i) af[i] = *(const bf16x8*)(fa + i * 16 * 32);
#pragma unroll
        for (int j = 0; j < 4; ++j) bfr[j] = *(const bf16x8*)(fb + j * 16 * 32);
        __syncthreads();
        const int kn = kt + 32;
        if (kn < 1024) {
            gA0 += 32; gA1 += 32;
            const u16* s0 = (kn < 512) ? pI0 + kn : pD0 + (kn - 512);
            const u16* s1 = (kn < 512) ? pI1 + kn : pD1 + (kn - 512);
            ld_lds16(gA0, lA0); ld_lds16(gA1, lA1);
            ld_lds16(s0, lB0); ld_lds16(s1, lB1);
        }
#pragma unroll
        for (int i = 0; i < 4; ++i)
#pragma unroll
            for (int j = 0; j < 4; ++j)
                acc[i][j] = __builtin_amdgcn_mfma_f32_16x16x32_bf16(
                    af[i], bfr[j], acc[i][j], 0, 0, 0);
    }

    const float* bias = (m0 < 640) ? b1r : b1t;
    const int boff = (m0 < 640) ? 0 : 640;
#pragma unroll
    for (int i = 0; i < 4; ++i) {
        const int mbase = m0 + wm + i * 16 + quad * 4;
        const float4 bbv = *(const float4*)&bias[mbase - boff];
#pragma unroll
        for (int j = 0; j < 4; ++j) {
            const int n = n0 + wn + j * 16 + lrow;
            f32x4 v = acc[i][j];
            float x0 = fmaxf(v[0] + bbv.x, 0.f), x1 = fmaxf(v[1] + bbv.y, 0.f);
            float x2 = fmaxf(v[2] + bbv.z, 0.f), x3 = fmaxf(v[3] + bbv.w, 0.f);
            ushort4 o;
            o.x = f2b(x0); o.y = f2b(x1); o.z = f2b(x2); o.w = f2b(x3);
            *(ushort4*)&Ct[(size_t)n * 1280 + mbase] = o;
        }
    }
}

// ---------------------------------------------------------------------------
// GEMM (BT) layer 2: Ct[n][out_off+m] = relu( sum_k A[m][k]*Bt[n][b_off+k]+b )
// 128m x 64n tile, BK=32, m97 staging.
// ---------------------------------------------------------------------------
__global__ __launch_bounds__(256) void gemm_bt(
    const u16* __restrict__ Ar, const u16* __restrict__ At,
    const float* __restrict__ biasr, const float* __restrict__ biast,
    const u16* __restrict__ Bt, u16* __restrict__ Ct,
    int Mh, int K, int bstride, int b_step, int ostride)
{
    __shared__ __align__(16) u16 lds_a[128 * 32];
    __shared__ __align__(16) u16 lds_b[64 * 32];

    const int t = threadIdx.x;
    const int n0 = blockIdx.x * 64;
    const int m0 = blockIdx.y * 128;
    const int branch = blockIdx.z;

    const u16* A = branch ? At : Ar;
    const float* bias = branch ? biast : biasr;
    const int b_off = branch * b_step;
    const int out_off = branch * Mh;

    const int w = t >> 6, l = t & 63;
    const int sr = l >> 2, sc = (l & 3) * 8;

    const u16* gA0 = A + (size_t)(m0 + w * 32 + sr) * K + sc;
    const u16* gA1 = gA0 + (size_t)16 * K;
    u16* lA0 = &lds_a[w * 1024];
    u16* lA1 = lA0 + 512;

    const u16* gB0 = Bt + (size_t)(n0 + w * 16 + sr) * bstride + b_off + sc;
    u16* lB0 = &lds_b[w * 512];

    const int wm = (w & 1) * 64;
    const int wn = (w >> 1) * 32;
    const int lrow = l & 15, quad = l >> 4;
    const u16* fa = &lds_a[(wm + lrow) * 32 + quad * 8];
    const u16* fb = &lds_b[(wn + lrow) * 32 + quad * 8];

    f32x4 acc[4][2];
#pragma unroll
    for (int i = 0; i < 4; ++i)
#pragma unroll
        for (int j = 0; j < 2; ++j)
            acc[i][j] = (f32x4){0.f, 0.f, 0.f, 0.f};

    ld_lds16(gA0, lA0); ld_lds16(gA1, lA1);
    ld_lds16(gB0, lB0);

    for (int kt = 0; kt < K; kt += 32) {
        __syncthreads();
        bf16x8 af[4], bfr[2];
#pragma unroll
        for (int i = 0; i < 4; ++i) af[i] = *(const bf16x8*)(fa + i * 16 * 32);
#pragma unroll
        for (int j = 0; j < 2; ++j) bfr[j] = *(const bf16x8*)(fb + j * 16 * 32);
        __syncthreads();
        if (kt + 32 < K) {
            gA0 += 32; gA1 += 32; gB0 += 32;
            ld_lds16(gA0, lA0); ld_lds16(gA1, lA1);
            ld_lds16(gB0, lB0);
        }
#pragma unroll
        for (int i = 0; i < 4; ++i)
#pragma unroll
            for (int j = 0; j < 2; ++j)
                acc[i][j] = __builtin_amdgcn_mfma_f32_16x16x32_bf16(
                    af[i], bfr[j], acc[i][j], 0, 0, 0);
    }

#pragma unroll
    for (int i = 0; i < 4; ++i) {
        const int mbase = m0 + wm + i * 16 + quad * 4;
        const float4 bbv = *(const float4*)&bias[mbase];
#pragma unroll
        for (int j = 0; j < 2; ++j) {
            const int n = n0 + wn + j * 16 + lrow;
            f32x4 v = acc[i][j];
            float x0 = fmaxf(v[0] + bbv.x, 0.f), x1 = fmaxf(v[1] + bbv.y, 0.f);
            float x2 = fmaxf(v[2] + bbv.z, 0.f), x3 = fmaxf(v[3] + bbv.w, 0.f);
            ushort4 o;
            o.x = f2b(x0); o.y = f2b(x1); o.z = f2b(x2); o.w = f2b(x3);
            *(ushort4*)&Ct[(size_t)n * ostride + out_off + mbase] = o;
        }
    }
}

// ---------------------------------------------------------------------------
// Fused layer 3 + layer 4 + slice + transpose + concat (f32 h3 in LDS).
// ---------------------------------------------------------------------------
__global__ __launch_bounds__(256) void gemm3_final_k(
    const u16* __restrict__ Ar, const u16* __restrict__ At,
    const float* __restrict__ b3r, const float* __restrict__ b3t,
    const u16* __restrict__ Bt,          // h2t, stride 512
    const float* __restrict__ w4r, const float* __restrict__ b4r,
    const float* __restrict__ w4t, const float* __restrict__ b4t,
    const int* __restrict__ objp, float* __restrict__ out)
{
    __shared__ __align__(16) u16 lds_a[128 * 32];
    __shared__ __align__(16) u16 lds_b[64 * 32];
    __shared__ __align__(16) float lds_h[64 * 132];  // h3 f32, padded stride
    __shared__ __align__(16) float lds_w[4 * 132];   // obj-selected w4 rows

    const int t = threadIdx.x;
    const int n0 = blockIdx.x * 64;
    const int branch = blockIdx.y;

    const u16* A = branch ? At : Ar;
    const float* bias = branch ? b3t : b3r;
    const int b_off = branch * 256;

    const int w = t >> 6, l = t & 63;
    const int sr = l >> 2, sc = (l & 3) * 8;

    const u16* gA0 = A + (size_t)(w * 32 + sr) * 256 + sc;
    const u16* gA1 = gA0 + (size_t)16 * 256;
    u16* lA0 = &lds_a[w * 1024];
    u16* lA1 = lA0 + 512;

    const u16* gB0 = Bt + (size_t)(n0 + w * 16 + sr) * 512 + b_off + sc;
    u16* lB0 = &lds_b[w * 512];

    const int wm = (w & 1) * 64;
    const int wn = (w >> 1) * 32;
    const int lrow = l & 15, quad = l >> 4;
    const u16* fa = &lds_a[(wm + lrow) * 32 + quad * 8];
    const u16* fb = &lds_b[(wn + lrow) * 32 + quad * 8];

    f32x4 acc[4][2];
#pragma unroll
    for (int i = 0; i < 4; ++i)
#pragma unroll
        for (int j = 0; j < 2; ++j)
            acc[i][j] = (f32x4){0.f, 0.f, 0.f, 0.f};

    ld_lds16(gA0, lA0); ld_lds16(gA1, lA1);
    ld_lds16(gB0, lB0);

    for (int kt = 0; kt < 256; kt += 32) {
        __syncthreads();
        bf16x8 af[4], bfr[2];
#pragma unroll
        for (int i = 0; i < 4; ++i) af[i] = *(const bf16x8*)(fa + i * 16 * 32);
#pragma unroll
        for (int j = 0; j < 2; ++j) bfr[j] = *(const bf16x8*)(fb + j * 16 * 32);
        __syncthreads();
        if (kt + 32 < 256) {
            gA0 += 32; gA1 += 32; gB0 += 32;
            ld_lds16(gA0, lA0); ld_lds16(gA1, lA1);
            ld_lds16(gB0, lB0);
        }
#pragma unroll
        for (int i = 0; i < 4; ++i)
#pragma unroll
            for (int j = 0; j < 2; ++j)
                acc[i][j] = __builtin_amdgcn_mfma_f32_16x16x32_bf16(
                    af[i], bfr[j], acc[i][j], 0, 0, 0);
    }

    // ---- h3 (f32, relu) -> LDS ----
#pragma unroll
    for (int i = 0; i < 4; ++i) {
        const int mbase = wm + i * 16 + quad * 4;
        const float4 bbv = *(const float4*)&bias[mbase];
#pragma unroll
        for (int j = 0; j < 2; ++j) {
            const int nl = wn + j * 16 + lrow;
            f32x4 v = acc[i][j];
            float4 x;
            x.x = fmaxf(v[0] + bbv.x, 0.f); x.y = fmaxf(v[1] + bbv.y, 0.f);
            x.z = fmaxf(v[2] + bbv.z, 0.f); x.w = fmaxf(v[3] + bbv.w, 0.f);
            *(float4*)&lds_h[nl * 132 + mbase] = x;
        }
    }
    // ---- obj-selected w4 rows -> LDS ----
    const int o = objp[0];
    const int NR = branch ? 3 : 4;
    const float* w4 = branch ? w4t : w4r;
    if (t < 128) {
        for (int r = 0; r < NR; ++r)
            lds_w[r * 132 + t] = w4[(size_t)(o * NR + r) * 128 + t];
    }
    __syncthreads();

    // ---- layer 4: thread t -> (n_local = t>>2, k = t&3) ----
    const int nl = t >> 2, k = t & 3;
    if (k < NR) {
        const float4* hp = (const float4*)&lds_h[nl * 132];
        const float4* wp4 = (const float4*)&lds_w[k * 132];
        float s = 0.f;
#pragma unroll
        for (int m4 = 0; m4 < 32; ++m4) {
            float4 h = hp[m4], ww = wp4[m4];
            s = fmaf(h.x, ww.x, s); s = fmaf(h.y, ww.y, s);
            s = fmaf(h.z, ww.z, s); s = fmaf(h.w, ww.w, s);
        }
        const int n = n0 + nl;
        if (branch == 0) out[(size_t)n * 4 + k] = s + b4r[o * 4 + k];
        else             out[32768 + (size_t)n * 3 + k] = s + b4t[o * 3 + k];
    }
}

// ---------------------------------------------------------------------------
extern "C" void kernel_launch(void* const* d_in, const int* in_sizes, int n_in,
                              void* d_out, int out_size, void* d_ws, size_t ws_size,
                              hipStream_t stream)
{
    const float* emb1 = (const float*)d_in[0];
    const float* emb2 = (const float*)d_in[1];
    const float* t1   = (const float*)d_in[2];
    const float* t2   = (const float*)d_in[3];
    const int*   obj  = (const int*)d_in[4];
    const float* w1r = (const float*)d_in[5];  const float* b1r = (const float*)d_in[6];
    const float* w2r = (const float*)d_in[7];  const float* b2r = (const float*)d_in[8];
    const float* w3r = (const float*)d_in[9];  const float* b3r = (const float*)d_in[10];
    const float* w4r = (const float*)d_in[11]; const float* b4r = (const float*)d_in[12];
    const float* w1t = (const float*)d_in[13]; const float* b1t = (const float*)d_in[14];
    const float* w2t = (const float*)d_in[15]; const float* b2t = (const float*)d_in[16];
    const float* w3t = (const float*)d_in[17]; const float* b3t = (const float*)d_in[18];
    const float* w4t = (const float*)d_in[19]; const float* b4t = (const float*)d_in[20];

    char* ws = (char*)d_ws;
    unsigned long long* keys = (unsigned long long*)ws;          // 64 KB
    u16* e1t = (u16*)(ws + (1u << 16));                          // 8 MB (8192x512)
    u16* e2t = (u16*)(ws + (1u << 16) + (8u << 20));             // 8 MB (8192x512)
    u16* h1t = (u16*)(ws + (1u << 16) + (16u << 20));            // 20 MB (8192x1280)
    u16* wp  = (u16*)(ws + (1u << 16) + (36u << 20));            // 3.25 MB
    u16* h2t = e1t;   // reuse: e1t dead after gemm1

    u16* w1rp = wp;            u16* w1tp = wp + 655360;
    u16* w2rp = wp + 1310720;  u16* w2tp = wp + 1474560;
    u16* w3rp = wp + 1638400;  u16* w3tp = wp + 1671168;

    hipMemsetAsync(keys, 0xFF, 8192 * sizeof(unsigned long long), stream);
    pack_w_k<<<832, 256, 0, stream>>>(w1r, w1t, w2r, w2t, w3r, w3t, wp);
    knn_k<<<dim3(64, 4), 256, 0, stream>>>(t1, t2, keys);
    transpose_k<<<dim3(128, 8, 2), 256, 0, stream>>>(emb1, emb2, e1t, e2t);
    // gemm1: w1p stacked rows 0..639=r, 640..1279=t; B gathered in staging.
    gemm1_k<<<dim3(64, 10), 256, 0, stream>>>(w1rp, b1r, b1t, keys, e1t, e2t, h1t);
    gemm_bt<<<dim3(128, 2, 2), 256, 0, stream>>>(w2rp, w2tp, b2r, b2t, h1t, h2t, 256, 640, 1280, 640, 512);
    gemm3_final_k<<<dim3(128, 2), 256, 0, stream>>>(w3rp, w3tp, b3r, b3t, h2t,
                                                    w4r, b4r, w4t, b4t, obj, (float*)d_out);
}

// Round 9
// 199.187 us; speedup vs baseline: 1.0127x; 1.0127x over previous
//
#include <hip/hip_runtime.h>

typedef unsigned short u16;
typedef __bf16 bf16x8 __attribute__((ext_vector_type(8)));
typedef float f32x4 __attribute__((ext_vector_type(4)));

__device__ __forceinline__ float b2f(u16 v) {
    return __uint_as_float(((unsigned int)v) << 16);
}
__device__ __forceinline__ u16 f2b(float f) {
    unsigned int u = __float_as_uint(f);
    u += 0x7fffu + ((u >> 16) & 1u);   // RNE
    return (u16)(u >> 16);
}

// async global->LDS, 16B/lane. Global side may be per-lane addresses;
// LDS side is wave-uniform base + lane*16B.
__device__ __forceinline__ void ld_lds16(const u16* g, u16* l) {
    __builtin_amdgcn_global_load_lds(
        (__attribute__((address_space(1))) void*)(uintptr_t)(const void*)g,
        (__attribute__((address_space(3))) void*)l, 16, 0, 0);
}

// Bank-conflict-free LDS chunk swizzle (global_load_lds keeps LDS writes
// linear, so we permute the GLOBAL chunk each lane fetches instead):
//   slot s of row r holds global chunk g where s = (g + (r>>1)) & 3.
// Staging lane l (row sr=l>>2, slot l&3) fetches g = ((l&3) - (sr>>1)) & 3.
// Fragment read for chunk=quad uses slot (quad + (lrow>>1)) & 3.
// Row bases (multiples of 16) don't alter (r>>1)&3. 16 rows -> all 8
// bank-groups, 2 lanes each: free 2-way [m136].
__device__ __forceinline__ int stage_chunk(int l) {
    return (((l & 3) - ((l >> 2) >> 1)) & 3) * 8;
}
__device__ __forceinline__ int frag_slot(int lrow, int quad) {
    return ((quad + (lrow >> 1)) & 3) * 8;
}

// ---------------------------------------------------------------------------
// Weight pre-pack: f32 -> bf16, segments laid out contiguously in ws.
// ---------------------------------------------------------------------------
__global__ void pack_w_k(const float* __restrict__ w1r, const float* __restrict__ w1t,
                         const float* __restrict__ w2r, const float* __restrict__ w2t,
                         const float* __restrict__ w3r, const float* __restrict__ w3t,
                         u16* __restrict__ dst)
{
    size_t i = (size_t)blockIdx.x * 2048 + (size_t)threadIdx.x * 8;
    const float* src; size_t off;
    if (i < 655360)       { src = w1r; off = 0; }
    else if (i < 1310720) { src = w1t; off = 655360; }
    else if (i < 1474560) { src = w2r; off = 1310720; }
    else if (i < 1638400) { src = w2t; off = 1474560; }
    else if (i < 1671168) { src = w3r; off = 1638400; }
    else                  { src = w3t; off = 1671168; }
    const float4 lo = *(const float4*)(src + (i - off));
    const float4 hi = *(const float4*)(src + (i - off) + 4);
    ushort4 o0, o1;
    o0.x = f2b(lo.x); o0.y = f2b(lo.y); o0.z = f2b(lo.z); o0.w = f2b(lo.w);
    o1.x = f2b(hi.x); o1.y = f2b(hi.y); o1.z = f2b(hi.z); o1.w = f2b(hi.w);
    *(ushort4*)(dst + i) = o0;
    *(ushort4*)(dst + i + 4) = o1;
}

// ---------------------------------------------------------------------------
// 1-NN (f32, mimics np: d2 = rr[i] + qq[j] - 2*g), atomicMin on (d2||idx) key.
// ---------------------------------------------------------------------------
__global__ void knn_k(const float* __restrict__ t1, const float* __restrict__ t2,
                      unsigned long long* __restrict__ keys)
{
    __shared__ float4 ref[128];   // x,y,z,rr
    const int t = threadIdx.x;
    const int rs = blockIdx.x;
    const int qb = blockIdx.y;
    if (t < 128) {
        int i = rs * 128 + t;
        float x = t1[i], y = t1[8192 + i], z = t1[16384 + i];
        float rr = __fadd_rn(__fadd_rn(__fmul_rn(x, x), __fmul_rn(y, y)), __fmul_rn(z, z));
        ref[t] = make_float4(x, y, z, rr);
    }
    __syncthreads();

    float qx[8], qy[8], qz[8], qq[8], bestd[8];
    int besti[8];
    const int q0 = qb * 2048 + t;
#pragma unroll
    for (int j = 0; j < 8; ++j) {
        int q = q0 + j * 256;
        qx[j] = t2[q]; qy[j] = t2[8192 + q]; qz[j] = t2[16384 + q];
        qq[j] = __fadd_rn(__fadd_rn(__fmul_rn(qx[j], qx[j]), __fmul_rn(qy[j], qy[j])),
                          __fmul_rn(qz[j], qz[j]));
        bestd[j] = __uint_as_float(0x7f800000u);
        besti[j] = 0;
    }
    for (int i = 0; i < 128; ++i) {
        float4 r = ref[i];
        int ridx = rs * 128 + i;
#pragma unroll
        for (int j = 0; j < 8; ++j) {
            float g = __fmaf_rn(qz[j], r.z, __fmaf_rn(qy[j], r.y, __fmul_rn(qx[j], r.x)));
            float d2 = __fsub_rn(__fadd_rn(r.w, qq[j]), __fmul_rn(2.0f, g));
            if (d2 < bestd[j]) { bestd[j] = d2; besti[j] = ridx; }
        }
    }
#pragma unroll
    for (int j = 0; j < 8; ++j) {
        unsigned long long key =
            ((unsigned long long)__float_as_uint(bestd[j]) << 32) | (unsigned int)besti[j];
        atomicMin(&keys[q0 + j * 256], key);
    }
}

// ---------------------------------------------------------------------------
// Both transposes in one dispatch: z=0 emb1->e1t, z=1 emb2->e2t (stride 512).
// ---------------------------------------------------------------------------
__global__ void transpose_k(const float* __restrict__ e1, const float* __restrict__ e2,
                            u16* __restrict__ o1, u16* __restrict__ o2)
{
    __shared__ float tile[64][65];
    const float* in = blockIdx.z ? e2 : e1;
    u16* out = blockIdx.z ? o2 : o1;
    const int t = threadIdx.x;
    const int n0 = blockIdx.x * 64, f0 = blockIdx.y * 64;
    const int c = t & 63, r4 = t >> 6;
#pragma unroll
    for (int p = 0; p < 16; ++p) {
        int fr = p * 4 + r4;
        tile[fr][c] = in[(size_t)(f0 + fr) * 8192 + n0 + c];
    }
    __syncthreads();
    const int fc = (t & 15) * 4;
    const int nr4 = t >> 4;
#pragma unroll
    for (int p = 0; p < 4; ++p) {
        int nr = p * 16 + nr4;
        ushort4 o;
        o.x = f2b(tile[fc + 0][nr]); o.y = f2b(tile[fc + 1][nr]);
        o.z = f2b(tile[fc + 2][nr]); o.w = f2b(tile[fc + 3][nr]);
        *(ushort4*)&out[(size_t)(n0 + nr) * 512 + f0 + fc] = o;
    }
}

// ---------------------------------------------------------------------------
// gemm1: h1t[n][m] = relu( sum_k A[m][k]*B[n][k] + bias[m] ), A = [w1r|w1t]
// (1280x1024). B row n: k<512 = e1t[idx[n]][k] (gather folded into staging),
// k>=512 = e2t[n][k-512]. 128x128 tile, BK=32, swizzled LDS chunks.
// ---------------------------------------------------------------------------
__global__ __launch_bounds__(256) void gemm1_k(
    const u16* __restrict__ A,
    const float* __restrict__ b1r, const float* __restrict__ b1t,
    const unsigned long long* __restrict__ keys,
    const u16* __restrict__ e1t, const u16* __restrict__ e2t,
    u16* __restrict__ Ct)
{
    __shared__ __align__(16) u16 lds_a[128 * 32];
    __shared__ __align__(16) u16 lds_b[128 * 32];

    const int t = threadIdx.x;
    const int n0 = blockIdx.x * 128;
    const int m0 = blockIdx.y * 128;
    const int w = t >> 6, l = t & 63;
    const int sr = l >> 2;
    const int sc = stage_chunk(l);          // swizzled global chunk

    const u16* gA0 = A + (size_t)(m0 + w * 32 + sr) * 1024 + sc;
    const u16* gA1 = gA0 + (size_t)16 * 1024;
    u16* lA0 = &lds_a[w * 1024];
    u16* lA1 = lA0 + 512;

    const int r0 = n0 + w * 32 + sr, r1 = r0 + 16;
    const int i0 = (int)(keys[r0] & 0xffffffffu);
    const int i1 = (int)(keys[r1] & 0xffffffffu);
    const u16* pI0 = e1t + (size_t)i0 * 512 + sc;   // indirect half (k<512)
    const u16* pI1 = e1t + (size_t)i1 * 512 + sc;
    const u16* pD0 = e2t + (size_t)r0 * 512 + sc;   // direct half (k>=512)
    const u16* pD1 = e2t + (size_t)r1 * 512 + sc;
    u16* lB0 = &lds_b[w * 1024];
    u16* lB1 = lB0 + 512;

    const int wm = (w & 1) * 64;
    const int wn = (w >> 1) * 64;
    const int lrow = l & 15, quad = l >> 4;
    const u16* fa = &lds_a[(wm + lrow) * 32 + frag_slot(lrow, quad)];
    const u16* fb = &lds_b[(wn + lrow) * 32 + frag_slot(lrow, quad)];

    f32x4 acc[4][4];
#pragma unroll
    for (int i = 0; i < 4; ++i)
#pragma unroll
        for (int j = 0; j < 4; ++j)
            acc[i][j] = (f32x4){0.f, 0.f, 0.f, 0.f};

    ld_lds16(gA0, lA0); ld_lds16(gA1, lA1);
    ld_lds16(pI0, lB0); ld_lds16(pI1, lB1);

    for (int kt = 0; kt < 1024; kt += 32) {
        __syncthreads();
        bf16x8 af[4], bfr[4];
#pragma unroll
        for (int i = 0; i < 4; ++i) af[i] = *(const bf16x8*)(fa + i * 16 * 32);
#pragma unroll
        for (int j = 0; j < 4; ++j) bfr[j] = *(const bf16x8*)(fb + j * 16 * 32);
        __syncthreads();
        const int kn = kt + 32;
        if (kn < 1024) {
            gA0 += 32; gA1 += 32;
            const u16* s0 = (kn < 512) ? pI0 + kn : pD0 + (kn - 512);
            const u16* s1 = (kn < 512) ? pI1 + kn : pD1 + (kn - 512);
            ld_lds16(gA0, lA0); ld_lds16(gA1, lA1);
            ld_lds16(s0, lB0); ld_lds16(s1, lB1);
        }
#pragma unroll
        for (int i = 0; i < 4; ++i)
#pragma unroll
            for (int j = 0; j < 4; ++j)
                acc[i][j] = __builtin_amdgcn_mfma_f32_16x16x32_bf16(
                    af[i], bfr[j], acc[i][j], 0, 0, 0);
    }

    const float* bias = (m0 < 640) ? b1r : b1t;
    const int boff = (m0 < 640) ? 0 : 640;
#pragma unroll
    for (int i = 0; i < 4; ++i) {
        const int mbase = m0 + wm + i * 16 + quad * 4;
        const float4 bbv = *(const float4*)&bias[mbase - boff];
#pragma unroll
        for (int j = 0; j < 4; ++j) {
            const int n = n0 + wn + j * 16 + lrow;
            f32x4 v = acc[i][j];
            float x0 = fmaxf(v[0] + bbv.x, 0.f), x1 = fmaxf(v[1] + bbv.y, 0.f);
            float x2 = fmaxf(v[2] + bbv.z, 0.f), x3 = fmaxf(v[3] + bbv.w, 0.f);
            ushort4 o;
            o.x = f2b(x0); o.y = f2b(x1); o.z = f2b(x2); o.w = f2b(x3);
            *(ushort4*)&Ct[(size_t)n * 1280 + mbase] = o;
        }
    }
}

// ---------------------------------------------------------------------------
// GEMM (BT) layer 2: Ct[n][out_off+m] = relu( sum_k A[m][k]*Bt[n][b_off+k]+b )
// 128m x 64n tile, BK=32, swizzled LDS chunks.
// ---------------------------------------------------------------------------
__global__ __launch_bounds__(256) void gemm_bt(
    const u16* __restrict__ Ar, const u16* __restrict__ At,
    const float* __restrict__ biasr, const float* __restrict__ biast,
    const u16* __restrict__ Bt, u16* __restrict__ Ct,
    int Mh, int K, int bstride, int b_step, int ostride)
{
    __shared__ __align__(16) u16 lds_a[128 * 32];
    __shared__ __align__(16) u16 lds_b[64 * 32];

    const int t = threadIdx.x;
    const int n0 = blockIdx.x * 64;
    const int m0 = blockIdx.y * 128;
    const int branch = blockIdx.z;

    const u16* A = branch ? At : Ar;
    const float* bias = branch ? biast : biasr;
    const int b_off = branch * b_step;
    const int out_off = branch * Mh;

    const int w = t >> 6, l = t & 63;
    const int sr = l >> 2;
    const int sc = stage_chunk(l);

    const u16* gA0 = A + (size_t)(m0 + w * 32 + sr) * K + sc;
    const u16* gA1 = gA0 + (size_t)16 * K;
    u16* lA0 = &lds_a[w * 1024];
    u16* lA1 = lA0 + 512;

    const u16* gB0 = Bt + (size_t)(n0 + w * 16 + sr) * bstride + b_off + sc;
    u16* lB0 = &lds_b[w * 512];

    const int wm = (w & 1) * 64;
    const int wn = (w >> 1) * 32;
    const int lrow = l & 15, quad = l >> 4;
    const u16* fa = &lds_a[(wm + lrow) * 32 + frag_slot(lrow, quad)];
    const u16* fb = &lds_b[(wn + lrow) * 32 + frag_slot(lrow, quad)];

    f32x4 acc[4][2];
#pragma unroll
    for (int i = 0; i < 4; ++i)
#pragma unroll
        for (int j = 0; j < 2; ++j)
            acc[i][j] = (f32x4){0.f, 0.f, 0.f, 0.f};

    ld_lds16(gA0, lA0); ld_lds16(gA1, lA1);
    ld_lds16(gB0, lB0);

    for (int kt = 0; kt < K; kt += 32) {
        __syncthreads();
        bf16x8 af[4], bfr[2];
#pragma unroll
        for (int i = 0; i < 4; ++i) af[i] = *(const bf16x8*)(fa + i * 16 * 32);
#pragma unroll
        for (int j = 0; j < 2; ++j) bfr[j] = *(const bf16x8*)(fb + j * 16 * 32);
        __syncthreads();
        if (kt + 32 < K) {
            gA0 += 32; gA1 += 32; gB0 += 32;
            ld_lds16(gA0, lA0); ld_lds16(gA1, lA1);
            ld_lds16(gB0, lB0);
        }
#pragma unroll
        for (int i = 0; i < 4; ++i)
#pragma unroll
            for (int j = 0; j < 2; ++j)
                acc[i][j] = __builtin_amdgcn_mfma_f32_16x16x32_bf16(
                    af[i], bfr[j], acc[i][j], 0, 0, 0);
    }

#pragma unroll
    for (int i = 0; i < 4; ++i) {
        const int mbase = m0 + wm + i * 16 + quad * 4;
        const float4 bbv = *(const float4*)&bias[mbase];
#pragma unroll
        for (int j = 0; j < 2; ++j) {
            const int n = n0 + wn + j * 16 + lrow;
            f32x4 v = acc[i][j];
            float x0 = fmaxf(v[0] + bbv.x, 0.f), x1 = fmaxf(v[1] + bbv.y, 0.f);
            float x2 = fmaxf(v[2] + bbv.z, 0.f), x3 = fmaxf(v[3] + bbv.w, 0.f);
            ushort4 o;
            o.x = f2b(x0); o.y = f2b(x1); o.z = f2b(x2); o.w = f2b(x3);
            *(ushort4*)&Ct[(size_t)n * ostride + out_off + mbase] = o;
        }
    }
}

// ---------------------------------------------------------------------------
// Fused layer 3 + layer 4 + slice + transpose + concat (f32 h3 in LDS).
// ---------------------------------------------------------------------------
__global__ __launch_bounds__(256) void gemm3_final_k(
    const u16* __restrict__ Ar, const u16* __restrict__ At,
    const float* __restrict__ b3r, const float* __restrict__ b3t,
    const u16* __restrict__ Bt,          // h2t, stride 512
    const float* __restrict__ w4r, const float* __restrict__ b4r,
    const float* __restrict__ w4t, const float* __restrict__ b4t,
    const int* __restrict__ objp, float* __restrict__ out)
{
    __shared__ __align__(16) u16 lds_a[128 * 32];
    __shared__ __align__(16) u16 lds_b[64 * 32];
    __shared__ __align__(16) float lds_h[64 * 132];
    __shared__ __align__(16) float lds_w[4 * 132];

    const int t = threadIdx.x;
    const int n0 = blockIdx.x * 64;
    const int branch = blockIdx.y;

    const u16* A = branch ? At : Ar;
    const float* bias = branch ? b3t : b3r;
    const int b_off = branch * 256;

    const int w = t >> 6, l = t & 63;
    const int sr = l >> 2;
    const int sc = stage_chunk(l);

    const u16* gA0 = A + (size_t)(w * 32 + sr) * 256 + sc;
    const u16* gA1 = gA0 + (size_t)16 * 256;
    u16* lA0 = &lds_a[w * 1024];
    u16* lA1 = lA0 + 512;

    const u16* gB0 = Bt + (size_t)(n0 + w * 16 + sr) * 512 + b_off + sc;
    u16* lB0 = &lds_b[w * 512];

    const int wm = (w & 1) * 64;
    const int wn = (w >> 1) * 32;
    const int lrow = l & 15, quad = l >> 4;
    const u16* fa = &lds_a[(wm + lrow) * 32 + frag_slot(lrow, quad)];
    const u16* fb = &lds_b[(wn + lrow) * 32 + frag_slot(lrow, quad)];

    f32x4 acc[4][2];
#pragma unroll
    for (int i = 0; i < 4; ++i)
#pragma unroll
        for (int j = 0; j < 2; ++j)
            acc[i][j] = (f32x4){0.f, 0.f, 0.f, 0.f};

    ld_lds16(gA0, lA0); ld_lds16(gA1, lA1);
    ld_lds16(gB0, lB0);

    for (int kt = 0; kt < 256; kt += 32) {
        __syncthreads();
        bf16x8 af[4], bfr[2];
#pragma unroll
        for (int i = 0; i < 4; ++i) af[i] = *(const bf16x8*)(fa + i * 16 * 32);
#pragma unroll
        for (int j = 0; j < 2; ++j) bfr[j] = *(const bf16x8*)(fb + j * 16 * 32);
        __syncthreads();
        if (kt + 32 < 256) {
            gA0 += 32; gA1 += 32; gB0 += 32;
            ld_lds16(gA0, lA0); ld_lds16(gA1, lA1);
            ld_lds16(gB0, lB0);
        }
#pragma unroll
        for (int i = 0; i < 4; ++i)
#pragma unroll
            for (int j = 0; j < 2; ++j)
                acc[i][j] = __builtin_amdgcn_mfma_f32_16x16x32_bf16(
                    af[i], bfr[j], acc[i][j], 0, 0, 0);
    }

    // ---- h3 (f32, relu) -> LDS ----
#pragma unroll
    for (int i = 0; i < 4; ++i) {
        const int mbase = wm + i * 16 + quad * 4;
        const float4 bbv = *(const float4*)&bias[mbase];
#pragma unroll
        for (int j = 0; j < 2; ++j) {
            const int nl = wn + j * 16 + lrow;
            f32x4 v = acc[i][j];
            float4 x;
            x.x = fmaxf(v[0] + bbv.x, 0.f); x.y = fmaxf(v[1] + bbv.y, 0.f);
            x.z = fmaxf(v[2] + bbv.z, 0.f); x.w = fmaxf(v[3] + bbv.w, 0.f);
            *(float4*)&lds_h[nl * 132 + mbase] = x;
        }
    }
    // ---- obj-selected w4 rows -> LDS ----
    const int o = objp[0];
    const int NR = branch ? 3 : 4;
    const float* w4 = branch ? w4t : w4r;
    if (t < 128) {
        for (int r = 0; r < NR; ++r)
            lds_w[r * 132 + t] = w4[(size_t)(o * NR + r) * 128 + t];
    }
    __syncthreads();

    // ---- layer 4: thread t -> (n_local = t>>2, k = t&3) ----
    const int nl = t >> 2, k = t & 3;
    if (k < NR) {
        const float4* hp = (const float4*)&lds_h[nl * 132];
        const float4* wp4 = (const float4*)&lds_w[k * 132];
        float s = 0.f;
#pragma unroll
        for (int m4 = 0; m4 < 32; ++m4) {
            float4 h = hp[m4], ww = wp4[m4];
            s = fmaf(h.x, ww.x, s); s = fmaf(h.y, ww.y, s);
            s = fmaf(h.z, ww.z, s); s = fmaf(h.w, ww.w, s);
        }
        const int n = n0 + nl;
        if (branch == 0) out[(size_t)n * 4 + k] = s + b4r[o * 4 + k];
        else             out[32768 + (size_t)n * 3 + k] = s + b4t[o * 3 + k];
    }
}

// ---------------------------------------------------------------------------
extern "C" void kernel_launch(void* const* d_in, const int* in_sizes, int n_in,
                              void* d_out, int out_size, void* d_ws, size_t ws_size,
                              hipStream_t stream)
{
    const float* emb1 = (const float*)d_in[0];
    const float* emb2 = (const float*)d_in[1];
    const float* t1   = (const float*)d_in[2];
    const float* t2   = (const float*)d_in[3];
    const int*   obj  = (const int*)d_in[4];
    const float* w1r = (const float*)d_in[5];  const float* b1r = (const float*)d_in[6];
    const float* w2r = (const float*)d_in[7];  const float* b2r = (const float*)d_in[8];
    const float* w3r = (const float*)d_in[9];  const float* b3r = (const float*)d_in[10];
    const float* w4r = (const float*)d_in[11]; const float* b4r = (const float*)d_in[12];
    const float* w1t = (const float*)d_in[13]; const float* b1t = (const float*)d_in[14];
    const float* w2t = (const float*)d_in[15]; const float* b2t = (const float*)d_in[16];
    const float* w3t = (const float*)d_in[17]; const float* b3t = (const float*)d_in[18];
    const float* w4t = (const float*)d_in[19]; const float* b4t = (const float*)d_in[20];

    char* ws = (char*)d_ws;
    unsigned long long* keys = (unsigned long long*)ws;          // 64 KB
    u16* e1t = (u16*)(ws + (1u << 16));                          // 8 MB (8192x512)
    u16* e2t = (u16*)(ws + (1u << 16) + (8u << 20));             // 8 MB (8192x512)
    u16* h1t = (u16*)(ws + (1u << 16) + (16u << 20));            // 20 MB (8192x1280)
    u16* wp  = (u16*)(ws + (1u << 16) + (36u << 20));            // 3.25 MB
    u16* h2t = e1t;   // reuse: e1t dead after gemm1

    u16* w1rp = wp;            u16* w1tp = wp + 655360;
    u16* w2rp = wp + 1310720;  u16* w2tp = wp + 1474560;
    u16* w3rp = wp + 1638400;  u16* w3tp = wp + 1671168;

    hipMemsetAsync(keys, 0xFF, 8192 * sizeof(unsigned long long), stream);
    pack_w_k<<<832, 256, 0, stream>>>(w1r, w1t, w2r, w2t, w3r, w3t, wp);
    knn_k<<<dim3(64, 4), 256, 0, stream>>>(t1, t2, keys);
    transpose_k<<<dim3(128, 8, 2), 256, 0, stream>>>(emb1, emb2, e1t, e2t);
    gemm1_k<<<dim3(64, 10), 256, 0, stream>>>(w1rp, b1r, b1t, keys, e1t, e2t, h1t);
    gemm_bt<<<dim3(128, 2, 2), 256, 0, stream>>>(w2rp, w2tp, b2r, b2t, h1t, h2t, 256, 640, 1280, 640, 512);
    gemm3_final_k<<<dim3(128, 2), 256, 0, stream>>>(w3rp, w3tp, b3r, b3t, h2t,
                                                    w4r, b4r, w4t, b4t, obj, (float*)d_out);
}